// Round 3
// baseline (1746.694 us; speedup 1.0000x reference)
//
#include <hip/hip_runtime.h>
#include <hip/hip_fp16.h>

#define B_  256
#define T_  2048
#define D_  128
#define H_  128
#define CH  32
#define NCH (T_ / CH)
#define XGW (4 * H_ + 8)                 // xgf row: 512 gates + pad

#define NLOG2E  (-1.4426950408889634f)   // i,f,o rows: sigm(x)=rcp(1+exp2(x*NLOG2E))
#define LOG2E2  ( 2.8853900817779268f)   // g rows:    tanh(x)=1-2*rcp(1+exp2(x*LOG2E2))

typedef __attribute__((ext_vector_type(8))) _Float16 half8v;
typedef __attribute__((ext_vector_type(2))) _Float16 half2v;
typedef __attribute__((ext_vector_type(4))) float    floatx4;

static __device__ __forceinline__ unsigned pkh(float a, float b) {
  return __builtin_bit_cast(unsigned, __builtin_amdgcn_cvt_pkrtz(a, b));
}
static __device__ __forceinline__ float h2f_lo(unsigned u) {
  return __half2float(__ushort_as_half((unsigned short)(u & 0xffffu)));
}
static __device__ __forceinline__ float h2f_hi(unsigned u) {
  return __half2float(__ushort_as_half((unsigned short)(u >> 16)));
}
// f16 dot2 with f32 accumulate (half-rate; used only for the 8-term fold)
static __device__ __forceinline__ float fdot2u(unsigned a, unsigned b, float c) {
  return __builtin_amdgcn_fdot2(__builtin_bit_cast(half2v, a),
                                __builtin_bit_cast(half2v, b), c, false);
}
// runtime 4-way select: 3 v_cndmask
static __device__ __forceinline__ float sel4r(float a, float b, float c, float d,
                                              int k) {
  float lo = (k & 1) ? b : a;
  float hi = (k & 1) ? d : c;
  return (k & 2) ? hi : lo;
}

// One block per batch element (256 blocks = 1/CU), 512 threads = 8 waves.
// Recurrence GEMV on v_pk_fma_f16 (full-rate packed: 64 MAC/cy/SIMD vs
// MFMA-GEMV's 26 with 15/16 columns wasted) -- R0-R2 established that the
// MFMA pipe and VALU never overlap here (serial dependence), so total
// issue+pipe work is what counts. 512 gates = 512 threads: one gate/lane,
// DENSE activations (2 trans/lane vs 10 on 3/4-masked lanes in R0).
// f16 accumulation split into 16 chains of 8 products, folded in f32 via
// fdot2 with (1,1): added noise ~3e-4 << existing ~4e-3 (xgf f16 storage).
// Gate gather (i,f,g,o of one unit -> every lane) is 3 in-wave ds_bpermute;
// the c state is 4-way lane-replicated, bitwise identical. One barrier/step.
__global__ __attribute__((amdgpu_flat_work_group_size(512, 512),
                          amdgpu_waves_per_eu(2, 2)))
void lstm_pk(
    const float* __restrict__ x,   const float* __restrict__ Wih,
    const float* __restrict__ Whh, const float* __restrict__ bih,
    const float* __restrict__ bhh, const float* __restrict__ Wo,
    const float* __restrict__ bo,  float* __restrict__ out)
{
  __shared__ unsigned       xs[CH][68];          // x chunk, f16 pairs (+4 pad)
  __shared__ unsigned short xgf[CH][XGW];        // xg preact (scaled+biased), f16
  __shared__ __align__(16) unsigned hbuf[2][64]; // h ping-pong, f16 pairs

  const int tid  = threadIdx.x;
  const int b    = blockIdx.x;
  const int l    = tid & 63;
  const int wv   = tid >> 6;
  const int quad = l >> 4;
  const int m16  = l & 15;
  const int t    = l >> 4;          // gate type of this lane, 0..3 (i,f,g,o)
  const int j    = l & 15;
  const int u    = wv * 16 + j;     // h-unit this lane's gate belongs to
  const int r    = t * 128 + u;     // row of Whh / column of xg

  // ---- Whh row r, pre-scaled, persistent in VGPRs: 128 f16 = 64 pairs
  const float s = (t == 2) ? LOG2E2 : NLOG2E;
  unsigned wd[64];
  {
    const float4* wp = (const float4*)(Whh + (size_t)r * H_);
    #pragma unroll
    for (int q = 0; q < 32; ++q) {
      float4 f = wp[q];
      wd[2 * q]     = pkh(f.x * s, f.y * s);
      wd[2 * q + 1] = pkh(f.z * s, f.w * s);
    }
  }

  // ---- Wih B-fragments for the input GEMM, pre-scaled by gate type (= wv>>1)
  const float sW = ((wv >> 1) == 2) ? LOG2E2 : NLOG2E;
  uint4 wb[4][4];
  float bv[4];
  #pragma unroll
  for (int nt = 0; nt < 4; ++nt) {
    int gcol = wv * 64 + nt * 16 + m16;
    const float4* p = (const float4*)(Wih + (size_t)gcol * D_);
    #pragma unroll
    for (int kf = 0; kf < 4; ++kf) {
      float4 f0 = p[kf * 8 + quad * 2];
      float4 f1 = p[kf * 8 + quad * 2 + 1];
      uint4 uu;
      uu.x = pkh(f0.x * sW, f0.y * sW);  uu.y = pkh(f0.z * sW, f0.w * sW);
      uu.z = pkh(f1.x * sW, f1.y * sW);  uu.w = pkh(f1.z * sW, f1.w * sW);
      wb[nt][kf] = uu;
    }
    bv[nt] = (bih[gcol] + bhh[gcol]) * sW;
  }

  if (tid < 128) hbuf[tid >> 6][tid & 63] = 0u;
  const floatx4 zf = {0.f, 0.f, 0.f, 0.f};
  float c = 0.0f;
  __syncthreads();

  const float* xb  = x + (size_t)b * T_ * D_;
  const int    a16 = (l ^ 16) << 2;   // ds_bpermute byte indices
  const int    a32 = (l ^ 32) << 2;

  for (int ch = 0; ch < NCH; ++ch) {
    // ---- stage x chunk (16 KB) as f16 pairs
    const float4* xsrc = (const float4*)(xb + (size_t)ch * CH * D_);
    #pragma unroll
    for (int i = 0; i < 2; ++i) {
      int fi = i * 512 + tid;
      float4 v = xsrc[fi];
      int tt = fi >> 5;
      int kp = (fi & 31) * 2;
      xs[tt][kp]     = pkh(v.x, v.y);
      xs[tt][kp + 1] = pkh(v.z, v.w);
    }
    __syncthreads();

    // ---- xg chunk: [32 t] x [512 g] = xs @ Wih_s^T (+ scaled bias), f16,
    // stored gate-row-major: xgf[t][gcol] (the step loop reads column r).
    #pragma unroll
    for (int mt = 0; mt < 2; ++mt) {
      half8v af[4];
      #pragma unroll
      for (int kf = 0; kf < 4; ++kf)
        af[kf] = __builtin_bit_cast(half8v,
                   *(const uint4*)&xs[mt * 16 + m16][kf * 16 + quad * 4]);
      #pragma unroll
      for (int nt = 0; nt < 4; ++nt) {
        floatx4 acc = zf;
        #pragma unroll
        for (int kf = 0; kf < 4; ++kf)
          acc = __builtin_amdgcn_mfma_f32_16x16x32_f16(
              af[kf], __builtin_bit_cast(half8v, wb[nt][kf]), acc, 0, 0, 0);
        int gcol = wv * 64 + nt * 16 + m16;
        #pragma unroll
        for (int rr = 0; rr < 4; ++rr) {
          int trow = mt * 16 + quad * 4 + rr;
          xgf[trow][gcol] =
              __half_as_ushort(__float2half(acc[rr] + bv[nt]));
        }
      }
    }
    __syncthreads();

    // ---- 32 recurrence steps: pk_fma GEMV + dense acts, one barrier each
    #pragma unroll 2
    for (int tt = 0; tt < CH; ++tt) {
      const int rp = tt & 1;
      // broadcast-read h (same address all lanes -> conflict-free)
      unsigned hs[64];
      const uint4* hb4 = (const uint4*)hbuf[rp];
      #pragma unroll
      for (int q = 0; q < 16; ++q)
        *(uint4*)&hs[4 * q] = hb4[q];
      float pre0 = __half2float(__ushort_as_half(xgf[tt][r]));

      // 64 pk_fma: 16 f16 chains of 8 products (8 packed accumulators)
      __half2 acc8[8];
      #pragma unroll
      for (int q = 0; q < 8; ++q)
        acc8[q] = __builtin_bit_cast(__half2, 0u);
      #pragma unroll
      for (int p = 0; p < 64; ++p)
        acc8[p & 7] = __hfma2(__builtin_bit_cast(__half2, hs[p]),
                              __builtin_bit_cast(__half2, wd[p]),
                              acc8[p & 7]);
      // fold the 8 packed partials in f32 (two independent fdot2 chains)
      const unsigned ONE2 = 0x3C003C00u;  // (1.0h, 1.0h)
      float cA = pre0, cB = 0.f;
      #pragma unroll
      for (int q = 0; q < 4; ++q)
        cA = fdot2u(__builtin_bit_cast(unsigned, acc8[q]), ONE2, cA);
      #pragma unroll
      for (int q = 4; q < 8; ++q)
        cB = fdot2u(__builtin_bit_cast(unsigned, acc8[q]), ONE2, cB);
      float pre = cA + cB;

      // dense uniform activation: r' = sigm-core; g-gate fixes to 1-2r'
      float rr  = __builtin_amdgcn_rcpf(1.0f + __builtin_amdgcn_exp2f(pre));
      float val = (t == 2) ? fmaf(-2.0f, rr, 1.0f) : rr;

      // gather the unit's 4 gates to every lane (in-wave, 3 bpermute)
      int vb  = __builtin_bit_cast(int, val);
      int w16 = __builtin_amdgcn_ds_bpermute(a16, vb);
      int w32 = __builtin_amdgcn_ds_bpermute(a32, vb);
      int w48 = __builtin_amdgcn_ds_bpermute(a32, w16);
      float S0 = val;
      float S1 = __builtin_bit_cast(float, w16);   // type t^1
      float S2 = __builtin_bit_cast(float, w32);   // type t^2
      float S3 = __builtin_bit_cast(float, w48);   // type t^3
      float gi = sel4r(S0, S1, S2, S3, t);
      float gf = sel4r(S0, S1, S2, S3, t ^ 1);
      float gg = sel4r(S0, S1, S2, S3, t ^ 2);
      float go = sel4r(S0, S1, S2, S3, t ^ 3);

      // c/h chain, 4-way replicated across t-groups (bitwise identical)
      c = gf * c + gi * gg;
      float tc = 1.0f - 2.0f * __builtin_amdgcn_rcpf(
                     1.0f + __builtin_amdgcn_exp2f(c * LOG2E2));
      float h = go * tc;
      if (t == 0)
        ((unsigned short*)hbuf[rp ^ 1])[u] = __half_as_ushort(__float2half(h));
      __syncthreads();
    }
  }

  // ---- out = h_last @ Wo^T + bo   (h_last in hbuf[0]: last step wrote buf 0)
  if (tid < H_) {
    float acc = bo[tid];
    const float4* wr = (const float4*)(Wo + (size_t)tid * H_);
    const uint2* hp = (const uint2*)hbuf[0];
    #pragma unroll
    for (int k4 = 0; k4 < 32; ++k4) {
      float4 w  = wr[k4];
      uint2  hu = hp[k4];
      acc += w.x * h2f_lo(hu.x) + w.y * h2f_hi(hu.x)
           + w.z * h2f_lo(hu.y) + w.w * h2f_hi(hu.y);
    }
    out[(size_t)b * H_ + tid] = acc;
  }
}

extern "C" void kernel_launch(void* const* d_in, const int* in_sizes, int n_in,
                              void* d_out, int out_size, void* d_ws, size_t ws_size,
                              hipStream_t stream) {
  (void)in_sizes; (void)n_in; (void)d_ws; (void)ws_size; (void)out_size;
  const float* x   = (const float*)d_in[0];
  const float* Wih = (const float*)d_in[1];
  const float* Whh = (const float*)d_in[2];
  const float* bih = (const float*)d_in[3];
  const float* bhh = (const float*)d_in[4];
  const float* Wo  = (const float*)d_in[5];
  const float* bo  = (const float*)d_in[6];
  lstm_pk<<<B_, 512, 0, stream>>>(x, Wih, Whh, bih, bhh, Wo, bo, (float*)d_out);
}

// Round 4
// 1355.323 us; speedup vs baseline: 1.2888x; 1.2888x over previous
//
#include <hip/hip_runtime.h>
#include <hip/hip_fp16.h>

#define B_  256
#define T_  2048
#define D_  128
#define H_  128
#define CH  32
#define NCH (T_ / CH)
#define XTP 36                           // xgT pitch in halves: 72B, 8B-aligned

#define NLOG2E  (-1.4426950408889634f)   // i,f,o rows: sigm(x)=rcp(1+exp2(x*NLOG2E))
#define LOG2E2  ( 2.8853900817779268f)   // g rows:    tanh(x)=1-2*rcp(1+exp2(x*LOG2E2))

typedef __attribute__((ext_vector_type(8))) _Float16 half8v;
typedef __attribute__((ext_vector_type(4))) float    floatx4;

static __device__ __forceinline__ unsigned pkh(float a, float b) {
  return __builtin_bit_cast(unsigned, __builtin_amdgcn_cvt_pkrtz(a, b));
}
static __device__ __forceinline__ float h2f_lo(unsigned u) {
  return __half2float(__ushort_as_half((unsigned short)(u & 0xffffu)));
}
static __device__ __forceinline__ float h2f_hi(unsigned u) {
  return __half2float(__ushort_as_half((unsigned short)(u >> 16)));
}
// select v[n] for runtime n in [0,4) -> 3 v_cndmask
#define SEL4(v, n) (((n) & 2) ? (((n) & 1) ? (v)[3] : (v)[2]) \
                              : (((n) & 1) ? (v)[1] : (v)[0]))

// v0 skeleton (MFMA GEMV, proven 620cy/SIMD) + DENSE epilogue:
// lane m16 = r + 4*g handles gate g of unit quad*4+r (C-layout cols are
// duplicated, so every lane holds all 4 gate-chains of its unit). One
// sigmoid-core per lane (2 trans vs v0's 8 on masked lanes), then a
// direction-free XOR all-gather of ACTIVATED gates (ds_swizzle xor4 +
// DPP ror8) and a parity-select c-chain replicated bitwise across the
// 4 gate-lanes. xg preacts live transposed in LDS (xgT[col][t]) so the
// step loop reads one b64 per 4 steps instead of b64every step.
__global__ __attribute__((amdgpu_flat_work_group_size(512, 512),
                          amdgpu_waves_per_eu(2, 2)))
void lstm_dense(
    const float* __restrict__ x,   const float* __restrict__ Wih,
    const float* __restrict__ Whh, const float* __restrict__ bih,
    const float* __restrict__ bhh, const float* __restrict__ Wo,
    const float* __restrict__ bo,  float* __restrict__ out)
{
  __shared__ unsigned       xs[CH][68];            // x chunk, f16 pairs (+pad)
  __shared__ __align__(16) unsigned short xgT[4 * H_][XTP]; // xg, col-major
  __shared__ __align__(16) unsigned hbuf[2][64];   // h ping-pong, f16 pairs

  const int tid  = threadIdx.x;
  const int b    = blockIdx.x;
  const int lane = tid & 63;
  const int wv   = tid >> 6;
  const int quad = lane >> 4;
  const int m16  = lane & 15;
  const int rsel = m16 & 3;          // unit offset within quad-row
  const int gsel = m16 >> 2;         // gate type this lane activates

  // ---- Whh A-fragments, pre-scaled, persistent: wa[mt][kf] = 8 f16 of
  // Whh_s[mt*128+wv*16+m16][kf*32+quad*8 .. +7]
  uint4 wa[4][4];
  #pragma unroll
  for (int mt = 0; mt < 4; ++mt) {
    float s = (mt == 2) ? LOG2E2 : NLOG2E;
    const float4* p = (const float4*)(Whh + (size_t)(mt * 128 + wv * 16 + m16) * H_);
    #pragma unroll
    for (int kf = 0; kf < 4; ++kf) {
      float4 f0 = p[kf * 8 + quad * 2];
      float4 f1 = p[kf * 8 + quad * 2 + 1];
      uint4 u;
      u.x = pkh(f0.x * s, f0.y * s);  u.y = pkh(f0.z * s, f0.w * s);
      u.z = pkh(f1.x * s, f1.y * s);  u.w = pkh(f1.z * s, f1.w * s);
      wa[mt][kf] = u;
    }
  }

  // ---- Wih B-fragments for the input GEMM, pre-scaled by gate type (= wv>>1)
  const float sW = ((wv >> 1) == 2) ? LOG2E2 : NLOG2E;
  uint4 wb[4][4];
  float bv[4];
  #pragma unroll
  for (int nt = 0; nt < 4; ++nt) {
    int gcol = wv * 64 + nt * 16 + m16;
    const float4* p = (const float4*)(Wih + (size_t)gcol * D_);
    #pragma unroll
    for (int kf = 0; kf < 4; ++kf) {
      float4 f0 = p[kf * 8 + quad * 2];
      float4 f1 = p[kf * 8 + quad * 2 + 1];
      uint4 u;
      u.x = pkh(f0.x * sW, f0.y * sW);  u.y = pkh(f0.z * sW, f0.w * sW);
      u.z = pkh(f1.x * sW, f1.y * sW);  u.w = pkh(f1.z * sW, f1.w * sW);
      wb[nt][kf] = u;
    }
    bv[nt] = (bih[gcol] + bhh[gcol]) * sW;
  }

  if (tid < 128) hbuf[tid >> 6][tid & 63] = 0u;
  const floatx4 zf = {0.f, 0.f, 0.f, 0.f};
  float c = 0.0f;
  __syncthreads();

  const float* xb = x + (size_t)b * T_ * D_;
  // this lane's xg column: unit-major, gate-minor
  const int mycol = ((wv * 16 + quad * 4 + rsel) << 2) | gsel;

  for (int ch = 0; ch < NCH; ++ch) {
    // ---- stage x chunk (16 KB) as f16 pairs
    const float4* xsrc = (const float4*)(xb + (size_t)ch * CH * D_);
    #pragma unroll
    for (int i = 0; i < 2; ++i) {
      int fi = i * 512 + tid;
      float4 v = xsrc[fi];
      int t  = fi >> 5;
      int kp = (fi & 31) * 2;
      xs[t][kp]     = pkh(v.x, v.y);
      xs[t][kp + 1] = pkh(v.z, v.w);
    }
    __syncthreads();

    // ---- xg chunk: [32 t] x [512 g] = xs @ Wih_s^T (+ scaled bias), f16,
    // stored TRANSPOSED: xgT[unit*4+gate][t] (one b64 write per nt,mt).
    #pragma unroll
    for (int mt = 0; mt < 2; ++mt) {
      half8v af[4];
      #pragma unroll
      for (int kf = 0; kf < 4; ++kf)
        af[kf] = __builtin_bit_cast(half8v,
                   *(const uint4*)&xs[mt * 16 + m16][kf * 16 + quad * 4]);
      #pragma unroll
      for (int nt = 0; nt < 4; ++nt) {
        floatx4 acc = zf;
        #pragma unroll
        for (int kf = 0; kf < 4; ++kf)
          acc = __builtin_amdgcn_mfma_f32_16x16x32_f16(
              af[kf], __builtin_bit_cast(half8v, wb[nt][kf]), acc, 0, 0, 0);
        int gcol = wv * 64 + nt * 16 + m16;
        int cu   = ((gcol & 127) << 2) | (gcol >> 7);
        uint2 pk;
        pk.x = pkh(acc[0] + bv[nt], acc[1] + bv[nt]);
        pk.y = pkh(acc[2] + bv[nt], acc[3] + bv[nt]);
        *(unsigned long long*)&xgT[cu][mt * 16 + quad * 4] =
            __builtin_bit_cast(unsigned long long, pk);
      }
    }
    __syncthreads();

    // ---- 32 recurrence steps (4 per xg b64 read)
    for (int tt4 = 0; tt4 < CH; tt4 += 4) {
      unsigned long long xq4 =
          *(const unsigned long long*)&xgT[mycol][tt4];
      #pragma unroll
      for (int tq = 0; tq < 4; ++tq) {
        const int tt = tt4 + tq;
        const int rp = tt & 1;
        // h as MFMA B-fragment, ALL lanes (dense epilogue reads all cols)
        uint4 hfr[4];
        #pragma unroll
        for (int kf = 0; kf < 4; ++kf)
          hfr[kf] = *(const uint4*)&hbuf[rp][kf * 16 + quad * 4];

        floatx4 a0, a1, a2, a3;
        {
          half8v hb = __builtin_bit_cast(half8v, hfr[0]);
          a0 = __builtin_amdgcn_mfma_f32_16x16x32_f16(
                   __builtin_bit_cast(half8v, wa[0][0]), hb, zf, 0, 0, 0);
          a1 = __builtin_amdgcn_mfma_f32_16x16x32_f16(
                   __builtin_bit_cast(half8v, wa[1][0]), hb, zf, 0, 0, 0);
          a2 = __builtin_amdgcn_mfma_f32_16x16x32_f16(
                   __builtin_bit_cast(half8v, wa[2][0]), hb, zf, 0, 0, 0);
          a3 = __builtin_amdgcn_mfma_f32_16x16x32_f16(
                   __builtin_bit_cast(half8v, wa[3][0]), hb, zf, 0, 0, 0);
        }
        #pragma unroll
        for (int kf = 1; kf < 4; ++kf) {
          half8v hb = __builtin_bit_cast(half8v, hfr[kf]);
          a0 = __builtin_amdgcn_mfma_f32_16x16x32_f16(
                   __builtin_bit_cast(half8v, wa[0][kf]), hb, a0, 0, 0, 0);
          a1 = __builtin_amdgcn_mfma_f32_16x16x32_f16(
                   __builtin_bit_cast(half8v, wa[1][kf]), hb, a1, 0, 0, 0);
          a2 = __builtin_amdgcn_mfma_f32_16x16x32_f16(
                   __builtin_bit_cast(half8v, wa[2][kf]), hb, a2, 0, 0, 0);
          a3 = __builtin_amdgcn_mfma_f32_16x16x32_f16(
                   __builtin_bit_cast(half8v, wa[3][kf]), hb, a3, 0, 0, 0);
        }

        // ---- dense epilogue: this lane = gate gsel of unit quad*4+rsel
        float s0 = SEL4(a0, rsel), s1 = SEL4(a1, rsel);
        float s2 = SEL4(a2, rsel), s3 = SEL4(a3, rsel);
        float sg = SEL4(((floatx4){s0, s1, s2, s3}), gsel);
        float xh = __half2float(__ushort_as_half(
                       (unsigned short)(xq4 >> (16 * tq))));
        float pre = sg + xh;
        float rr  = __builtin_amdgcn_rcpf(1.0f + __builtin_amdgcn_exp2f(pre));
        float val = (gsel == 2) ? fmaf(-2.0f, rr, 1.0f) : rr;

        // XOR all-gather of activated gates: R[d] = gate (gsel^d)
        int vb = __builtin_bit_cast(int, val);
        int r1 = __builtin_amdgcn_ds_swizzle(vb, 0x101F);          // lane^4
        int r2 = __builtin_amdgcn_update_dpp(0, vb, 0x128, 0xF, 0xF, false); // row ror8 == lane^8
        int r3 = __builtin_amdgcn_ds_swizzle(r2, 0x101F);          // lane^12
        float R1 = __builtin_bit_cast(float, r1);
        float R2 = __builtin_bit_cast(float, r2);
        float R3 = __builtin_bit_cast(float, r3);

        // gate k lives in R[k ^ gsel]; parity-select the c-chain terms
        const bool b0 = (gsel & 1) != 0, b1 = (gsel & 2) != 0;
        float P  = b0 ? R1 * R3 : val * R2;                  // gi*gg
        float gf = b0 ? (b1 ? R2 : val) : (b1 ? R3 : R1);    // R[1^gsel]
        float go = b0 ? (b1 ? val : R2) : (b1 ? R1 : R3);    // R[3^gsel]

        c = fmaf(gf, c, P);
        float tc = 1.0f - 2.0f * __builtin_amdgcn_rcpf(
                       1.0f + __builtin_amdgcn_exp2f(c * LOG2E2));
        float h = go * tc;
        if (gsel == 0)   // 16 lanes write the wave's 16 units
          ((unsigned short*)hbuf[rp ^ 1])[wv * 16 + quad * 4 + rsel] =
              __half_as_ushort(__float2half(h));
        __syncthreads();
      }
    }
  }

  // ---- out = h_last @ Wo^T + bo   (h_last in hbuf[0]: last step wrote buf 0)
  if (tid < H_) {
    float acc = bo[tid];
    const float4* wr = (const float4*)(Wo + (size_t)tid * H_);
    const uint2* hp = (const uint2*)hbuf[0];
    #pragma unroll
    for (int k4 = 0; k4 < 32; ++k4) {
      float4 w  = wr[k4];
      uint2  hu = hp[k4];
      acc += w.x * h2f_lo(hu.x) + w.y * h2f_hi(hu.x)
           + w.z * h2f_lo(hu.y) + w.w * h2f_hi(hu.y);
    }
    out[(size_t)b * H_ + tid] = acc;
  }
}

extern "C" void kernel_launch(void* const* d_in, const int* in_sizes, int n_in,
                              void* d_out, int out_size, void* d_ws, size_t ws_size,
                              hipStream_t stream) {
  (void)in_sizes; (void)n_in; (void)d_ws; (void)ws_size; (void)out_size;
  const float* x   = (const float*)d_in[0];
  const float* Wih = (const float*)d_in[1];
  const float* Whh = (const float*)d_in[2];
  const float* bih = (const float*)d_in[3];
  const float* bhh = (const float*)d_in[4];
  const float* Wo  = (const float*)d_in[5];
  const float* bo  = (const float*)d_in[6];
  lstm_dense<<<B_, 512, 0, stream>>>(x, Wih, Whh, bih, bhh, Wo, bo, (float*)d_out);
}